// Round 12
// baseline (428.367 us; speedup 1.0000x reference)
//
#include <hip/hip_runtime.h>
#include <cstdint>
#include <cstddef>

// Sizes
#define LSEQ 4096
#define DI   512
#define NSTATE 16
#define TC 32     // scan chunk length
#define NCH 128   // number of chunks (LSEQ/TC)

// Workspace layout (floats):
//  xm   : [8][4096][512] @ 0          (dead after convx -> reused by ap/ps)
//  gate : [8][4096][512] @ 16,777,216
//  xs   : [8][4096][512] @ 33,554,432 (becomes y in-place after scan3)
//  dbl  : [8][4096][48]  @ 50,331,648
//  split: bf16 bufs      @ 51,904,512 (dead after gemm_in)
//  WxT  : [48][512]      @ 54,263,808
//  ap   : [8][128][512][16] @ 0          (aliases xm)
//  ps   : [8][128][512][16] @ 8,388,608  (aliases xm upper half)
#define XM_OFF    0
#define GATE_OFF  16777216
#define XS_OFF    33554432
#define DBL_OFF   50331648
#define SPLIT_OFF 51904512
#define WXT_OFF   54263808
#define AP_OFF    0
#define PS_OFF    8388608

typedef unsigned short u16;
typedef __attribute__((ext_vector_type(8))) short s8v;    // 8 bf16 (4 VGPR)
typedef __attribute__((ext_vector_type(4))) float f4v;    // 4 fp32 acc
typedef __attribute__((ext_vector_type(4))) unsigned int u32x4;

#ifndef __has_builtin
#define __has_builtin(x) 0
#endif
#if __has_builtin(__builtin_amdgcn_global_load_lds)
#define USE_GLL 1
#else
#define USE_GLL 0
#endif

__device__ __forceinline__ float silu_f(float v) {
  return v * __frcp_rn(1.f + __expf(-v));
}
__device__ __forceinline__ float softplus_f(float v) {
  return fmaxf(v, 0.f) + __logf(1.f + __expf(-fabsf(v)));
}
__device__ __forceinline__ u16 bf16_hi(float v) {   // RNE truncate to bf16
  unsigned u = __float_as_uint(v);
  return (u16)((u + 0x7fffu + ((u >> 16) & 1u)) >> 16);
}
__device__ __forceinline__ float bf16_f(u16 h) { return __uint_as_float(((unsigned)h) << 16); }

__device__ __forceinline__ void gld16(const u16* g, u16* l, int lane) {
#if USE_GLL
  __builtin_amdgcn_global_load_lds((const __attribute__((address_space(1))) void*)g,
                                   (__attribute__((address_space(3))) void*)l, 16, 0, 0);
#else
  *(u32x4*)(l + lane * 8) = *(const u32x4*)g;
#endif
}

// powers r^1..r^16 via log-depth ladder (15 muls, depth ~4)
__device__ __forceinline__ void pow_ladder(float r, float* a) {
  const float r2 = r * r, r4 = r2 * r2, r8 = r4 * r4;
  a[0] = r;        a[1] = r2;       a[2] = r2 * r;   a[3] = r4;
  a[4] = r4 * r;   a[5] = r4 * r2;  a[6] = r4 * a[2]; a[7] = r8;
  a[8] = r8 * r;   a[9] = r8 * r2;  a[10] = r8 * a[2]; a[11] = r8 * r4;
  a[12] = r8 * a[4]; a[13] = r8 * a[5]; a[14] = r8 * a[6]; a[15] = r8 * r8;
}

// ---------------------------------------------------------------------------
// k_split: transpose fp32 [R][C] (batched) -> bf16 hi/lo [C][R]
// ---------------------------------------------------------------------------
__global__ __launch_bounds__(256) void k_split(const float* __restrict__ in,
                                               u16* __restrict__ oh,
                                               u16* __restrict__ ol,
                                               int R, int C) {
  __shared__ float tile[64][65];
  const size_t zoff = (size_t)blockIdx.z * R * C;
  in += zoff; oh += zoff; ol += zoff;
  const int c0 = blockIdx.x << 6, r0 = blockIdx.y << 6;
  const int tid = threadIdx.x;
  const int tx = tid & 63, ty = tid >> 6;
#pragma unroll
  for (int i = 0; i < 16; ++i) {
    const int r = ty + (i << 2);
    tile[r][tx] = in[(size_t)(r0 + r) * C + c0 + tx];
  }
  __syncthreads();
#pragma unroll
  for (int i = 0; i < 16; ++i) {
    const int cc = ty + (i << 2);
    const float v = tile[tx][cc];              // = in[r0+tx][c0+cc]
    const u16 h = bf16_hi(v);
    const size_t o = (size_t)(c0 + cc) * R + r0 + tx;
    oh[o] = h;
    ol[o] = bf16_hi(v - bf16_f(h));
  }
}

// ---------------------------------------------------------------------------
// k_wxT: WxT[c][k] = Wx[k][c]  (48 x 512)
// ---------------------------------------------------------------------------
__global__ __launch_bounds__(256) void k_wxT(const float* __restrict__ Wx,
                                             float* __restrict__ WxT) {
  const int i = blockIdx.x * 256 + threadIdx.x;   // 0..24575
  const int c = i >> 9, k = i & 511;
  WxT[i] = Wx[(size_t)k * 48 + c];
}

// ---------------------------------------------------------------------------
// Kernel 1: [xm|gate] = z @ W_in via bf16x2-split MFMA, 128x128 tile, BK=32.
// ---------------------------------------------------------------------------
__global__ __launch_bounds__(256) void k_gemm_in_mfma(const u16* __restrict__ xTh,
                                                      const u16* __restrict__ xTl,
                                                      const u16* __restrict__ Wh,
                                                      const u16* __restrict__ Wl,
                                                      float* __restrict__ xm,
                                                      float* __restrict__ gate) {
  __shared__ __attribute__((aligned(16))) u16 lds[4 * 128 * 32];  // Ah,Al,Bh,Bl
  u16* Ah = lds;
  u16* Al = lds + 4096;
  u16* Bh = lds + 8192;
  u16* Bl = lds + 12288;
  const int rt = blockIdx.x;            // 256 row tiles (128 rows each)
  const int nt = blockIdx.y;            // 8 col tiles (128 cols each)
  const int seq = rt >> 5, hl2 = rt & 31;
  const int b = seq & 1, dir = seq >> 1;
  const int tid = threadIdx.x;
  const int lane = tid & 63, wid = tid >> 6;
  const int wr = wid >> 1, wc = wid & 1;

  const u16* gsrc = (wid == 0) ? xTh : (wid == 1) ? xTl : (wid == 2) ? Wh : Wl;
  u16* ldst = lds + (wid << 12);
  size_t roff[8];
#pragma unroll
  for (int i = 0; i < 8; ++i) {
    const int r = (i << 4) + (lane >> 2);
    size_t off;
    if (wid < 2) {
      const int hl = (hl2 << 1) + (r >> 6), w = r & 63;
      const int hp = (dir & 2) ? 63 - hl : hl;
      const int wp = (dir & 1) ? 63 - w : w;
      off = ((size_t)((b << 12) + (hp << 6) + wp)) << 8;
    } else {
      off = ((size_t)((nt << 7) + r)) << 8;
    }
    roff[i] = off + ((lane & 3) << 3);
  }

  f4v acc[4][4];
  const f4v z4 = {0.f, 0.f, 0.f, 0.f};
#pragma unroll
  for (int m = 0; m < 4; ++m)
#pragma unroll
    for (int n = 0; n < 4; ++n) acc[m][n] = z4;

  const int fr = lane & 15;
  const int kg = (lane >> 4) << 3;

  for (int kc = 0; kc < 256; kc += 32) {
    __syncthreads();
#pragma unroll
    for (int i = 0; i < 8; ++i) gld16(gsrc + roff[i] + kc, ldst + (i << 9), lane);
    __syncthreads();
    s8v Afh[4], Afl[4], Bfh[4], Bfl[4];
#pragma unroll
    for (int m = 0; m < 4; ++m) {
      const int row = (wr << 6) + (m << 4) + fr;
      Afh[m] = *(const s8v*)&Ah[row * 32 + kg];
      Afl[m] = *(const s8v*)&Al[row * 32 + kg];
    }
#pragma unroll
    for (int n = 0; n < 4; ++n) {
      const int row = (wc << 6) + (n << 4) + fr;
      Bfh[n] = *(const s8v*)&Bh[row * 32 + kg];
      Bfl[n] = *(const s8v*)&Bl[row * 32 + kg];
    }
#pragma unroll
    for (int m = 0; m < 4; ++m)
#pragma unroll
      for (int n = 0; n < 4; ++n) {
        acc[m][n] = __builtin_amdgcn_mfma_f32_16x16x32_bf16(Afh[m], Bfh[n], acc[m][n], 0, 0, 0);
        acc[m][n] = __builtin_amdgcn_mfma_f32_16x16x32_bf16(Afh[m], Bfl[n], acc[m][n], 0, 0, 0);
        acc[m][n] = __builtin_amdgcn_mfma_f32_16x16x32_bf16(Afl[m], Bfh[n], acc[m][n], 0, 0, 0);
      }
  }
  const int rg = (lane >> 4) << 2;
  float* obuf = (nt & 4) ? gate : xm;
  const int ncol = (nt & 3) << 7;
  float* obase = obuf + ((size_t)((rt << 7) + (wr << 6) + rg)) * DI + ncol + (wc << 6) + fr;
#pragma unroll
  for (int m = 0; m < 4; ++m)
#pragma unroll
    for (int n = 0; n < 4; ++n)
#pragma unroll
      for (int j = 0; j < 4; ++j)
        obase[(size_t)((m << 4) + j) * DI + (n << 4)] = acc[m][n][j];
}

// ---------------------------------------------------------------------------
// Kernel 2+3 fused (k_convx) v3: 19-row float2 preload pinned with
// sched_barrier(0) (compiler may not sink loads); gemm phase reads WxT
// (pre-transposed) as float4 (4x fewer load instructions, L1-hot).
// ---------------------------------------------------------------------------
__global__ __launch_bounds__(256) void k_convx(const float* __restrict__ xmb,
                                               const float* __restrict__ cw,
                                               const float* __restrict__ cb,
                                               const float* __restrict__ WxT,
                                               float* __restrict__ xs,
                                               float* __restrict__ dbl) {
  __shared__ float xsh[16][512];
  const int rb  = blockIdx.x;
  const int tid = threadIdx.x;
  const int r0g = rb << 4;            // global row (seq*4096 + t)
  const int t0  = r0g & 4095;         // within-seq t (0 only at seq start)
  const int d2  = tid << 1;           // 2 adjacent d columns per thread
  const float4 wA = *(const float4*)&cw[d2 * 4];
  const float4 wB = *(const float4*)&cw[d2 * 4 + 4];
  const float bx = cb[d2], by = cb[d2 + 1];

  float2 xv[19];
#pragma unroll
  for (int i = 0; i < 16; ++i)
    xv[i + 3] = *(const float2*)&xmb[(size_t)(r0g + i) * DI + d2];
  if (t0 != 0) {
    xv[0] = *(const float2*)&xmb[((size_t)r0g - 3) * DI + d2];
    xv[1] = *(const float2*)&xmb[((size_t)r0g - 2) * DI + d2];
    xv[2] = *(const float2*)&xmb[((size_t)r0g - 1) * DI + d2];
  } else {
    xv[0] = make_float2(0.f, 0.f);
    xv[1] = make_float2(0.f, 0.f);
    xv[2] = make_float2(0.f, 0.f);
  }
  __builtin_amdgcn_sched_barrier(0);   // pin: all 19 loads issued before compute
  float* xsg = xs + (size_t)r0g * DI + d2;
#pragma unroll
  for (int i = 0; i < 16; ++i) {
    const float vx = fmaf(wA.x, xv[i].x, fmaf(wA.y, xv[i + 1].x,
                     fmaf(wA.z, xv[i + 2].x, fmaf(wA.w, xv[i + 3].x, bx))));
    const float vy = fmaf(wB.x, xv[i].y, fmaf(wB.y, xv[i + 1].y,
                     fmaf(wB.z, xv[i + 2].y, fmaf(wB.w, xv[i + 3].y, by))));
    float2 sv;
    sv.x = silu_f(vx);
    sv.y = silu_f(vy);
    *(float2*)&xsh[i][d2] = sv;
    *(float2*)&xsg[(size_t)i * DI] = sv;
  }
  __syncthreads();
  if (tid < 192) {
    const int col = tid % 48;
    const int rg  = tid / 48;
    const float* wrow = WxT + (size_t)col * 512;
    float a0 = 0.f, a1 = 0.f, a2 = 0.f, a3 = 0.f;
    for (int k = 0; k < 512; k += 4) {
      const float4 wv = *(const float4*)&wrow[k];
      const float4 x0 = *(const float4*)&xsh[rg * 4 + 0][k];
      const float4 x1 = *(const float4*)&xsh[rg * 4 + 1][k];
      const float4 x2 = *(const float4*)&xsh[rg * 4 + 2][k];
      const float4 x3 = *(const float4*)&xsh[rg * 4 + 3][k];
      a0 = fmaf(x0.x, wv.x, fmaf(x0.y, wv.y, fmaf(x0.z, wv.z, fmaf(x0.w, wv.w, a0))));
      a1 = fmaf(x1.x, wv.x, fmaf(x1.y, wv.y, fmaf(x1.z, wv.z, fmaf(x1.w, wv.w, a1))));
      a2 = fmaf(x2.x, wv.x, fmaf(x2.y, wv.y, fmaf(x2.z, wv.z, fmaf(x2.w, wv.w, a2))));
      a3 = fmaf(x3.x, wv.x, fmaf(x3.y, wv.y, fmaf(x3.z, wv.z, fmaf(x3.w, wv.w, a3))));
    }
    const size_t base = ((size_t)rb * 16 + rg * 4) * 48 + col;
    dbl[base] = a0; dbl[base + 48] = a1; dbl[base + 96] = a2; dbl[base + 144] = a3;
  }
}

// ---------------------------------------------------------------------------
// Kernel 4 (scan pass 1): r = sigmoid(-dtp) == exp(-softplus(dtp));
// dtv = -log(r). One rcp+2 trans per t in fast path.
// ---------------------------------------------------------------------------
__global__ __launch_bounds__(256) void k_scan1(const float* __restrict__ xs,
                                               const float* __restrict__ dbl,
                                               const float* __restrict__ Wdt,
                                               const float* __restrict__ bdt,
                                               const float* __restrict__ Alog,
                                               float* __restrict__ aprod,
                                               float* __restrict__ pstate) {
  __shared__ float dsh[TC * 48];
  const int ch = blockIdx.x, seq = blockIdx.y;
  const int tid = threadIdx.x;
  const int d = (blockIdx.z << 8) + tid;
  const int t0 = ch * TC;
  const float* dsrc = dbl + ((size_t)seq * LSEQ + t0) * 48;
#pragma unroll
  for (int i = 0; i < 6; ++i) dsh[tid + (i << 8)] = dsrc[tid + (i << 8)];
  float wdt[16], Aa[16], st[16], P[16];
#pragma unroll
  for (int k = 0; k < 16; ++k) wdt[k] = Wdt[(size_t)k * DI + d];
  const float bd = bdt[d];
  bool fast = true;
#pragma unroll
  for (int s = 0; s < NSTATE; ++s) {
    const float Av = __expf(Alog[d * NSTATE + s]);
    Aa[s] = -Av;
    fast = fast && (fabsf(Av - (float)(s + 1)) < 1e-3f);
    st[s] = 0.f; P[s] = 1.f;
  }
  const float* xsrc = xs + ((size_t)seq * LSEQ + t0) * DI + d;
  __syncthreads();
  if (fast) {
    float Rp = 1.f;
    for (int t = 0; t < TC; ++t) {
      const float* dr = &dsh[t * 48];
      float dtp = bd;
#pragma unroll
      for (int k = 0; k < 16; ++k) dtp = fmaf(dr[k], wdt[k], dtp);
      const float r = __frcp_rn(1.f + __expf(fminf(dtp, 80.f)));
      const float dtv = -__logf(r);
      const float u = dtv * xsrc[(size_t)t * DI];
      float a[16];
      pow_ladder(r, a);
      Rp *= r;
#pragma unroll
      for (int s = 0; s < NSTATE; ++s) st[s] = fmaf(a[s], st[s], u * dr[16 + s]);
    }
    pow_ladder(Rp, P);
  } else {
    for (int t = 0; t < TC; ++t) {
      const float* dr = &dsh[t * 48];
      float dtp = bd;
#pragma unroll
      for (int k = 0; k < 16; ++k) dtp = fmaf(dr[k], wdt[k], dtp);
      const float dtv = softplus_f(dtp);
      const float u = dtv * xsrc[(size_t)t * DI];
#pragma unroll
      for (int s = 0; s < NSTATE; ++s) {
        const float a = __expf(dtv * Aa[s]);
        st[s] = fmaf(a, st[s], u * dr[16 + s]);
        P[s] *= a;
      }
    }
  }
  float* ap = aprod  + (((size_t)seq * NCH + ch) * DI + d) * NSTATE;
  float* pp = pstate + (((size_t)seq * NCH + ch) * DI + d) * NSTATE;
#pragma unroll
  for (int s = 0; s < NSTATE; s += 4) {
    *(float4*)&ap[s] = make_float4(P[s], P[s + 1], P[s + 2], P[s + 3]);
    *(float4*)&pp[s] = make_float4(st[s], st[s + 1], st[s + 2], st[s + 3]);
  }
}

// ---------------------------------------------------------------------------
// Kernel 5 (scan pass 2): cross-chunk scan; pstate becomes hinit in-place.
// ---------------------------------------------------------------------------
__global__ __launch_bounds__(256) void k_scan2(const float* __restrict__ aprod,
                                               float* __restrict__ pstate) {
  const int flat = blockIdx.x * 256 + threadIdx.x;
  const int seq = flat >> 13;
  const int rem = flat & 8191;
  const size_t stride = (size_t)DI * NSTATE;
  const size_t base = (size_t)seq * NCH * stride + rem;
  float h = 0.f;
  for (int ch = 0; ch < NCH; ++ch) {
    const size_t o = base + (size_t)ch * stride;
    const float a = aprod[o];
    const float bsum = pstate[o];
    pstate[o] = h;
    h = fmaf(a, h, bsum);
  }
}

// ---------------------------------------------------------------------------
// Kernel 6 (scan pass 3): same sigmoid fast path; y over xs in place.
// ---------------------------------------------------------------------------
__global__ __launch_bounds__(256) void k_scan3(const float* __restrict__ gate,
                                               float* __restrict__ xs,
                                               const float* __restrict__ dbl,
                                               const float* __restrict__ Wdt,
                                               const float* __restrict__ bdt,
                                               const float* __restrict__ Alog,
                                               const float* __restrict__ Dv,
                                               const float* __restrict__ hinit) {
  __shared__ float dsh[TC * 48];
  const int ch = blockIdx.x, seq = blockIdx.y;
  const int tid = threadIdx.x;
  const int d = (blockIdx.z << 8) + tid;
  const int t0 = ch * TC;
  const float* dsrc = dbl + ((size_t)seq * LSEQ + t0) * 48;
#pragma unroll
  for (int i = 0; i < 6; ++i) dsh[tid + (i << 8)] = dsrc[tid + (i << 8)];
  float wdt[16], Aa[16], st[16];
#pragma unroll
  for (int k = 0; k < 16; ++k) wdt[k] = Wdt[(size_t)k * DI + d];
  const float bd = bdt[d];
  const float Dp = Dv[d];
  const float* hp = hinit + (((size_t)seq * NCH + ch) * DI + d) * NSTATE;
  bool fast = true;
#pragma unroll
  for (int s = 0; s < NSTATE; ++s) {
    const float Av = __expf(Alog[d * NSTATE + s]);
    Aa[s] = -Av;
    fast = fast && (fabsf(Av - (float)(s + 1)) < 1e-3f);
    st[s] = hp[s];
  }
  float* xrow = xs + ((size_t)seq * LSEQ + t0) * DI + d;
  const float* grow = gate + ((size_t)seq * LSEQ + t0) * DI + d;
  __syncthreads();
  if (fast) {
    for (int t = 0; t < TC; ++t) {
      const float* dr = &dsh[t * 48];
      float dtp = bd;
#pragma unroll
      for (int k = 0; k < 16; ++k) dtp = fmaf(dr[k], wdt[k], dtp);
      const float r = __frcp_rn(1.f + __expf(fminf(dtp, 80.f)));
      const float dtv = -__logf(r);
      const float xsv = xrow[(size_t)t * DI];
      const float u = dtv * xsv;
      float a[16];
      pow_ladder(r, a);
      float y = 0.f;
#pragma unroll
      for (int s = 0; s < NSTATE; ++s) {
        st[s] = fmaf(a[s], st[s], u * dr[16 + s]);
        y = fmaf(st[s], dr[32 + s], y);
      }
      y = fmaf(xsv, Dp, y);
      y *= silu_f(grow[(size_t)t * DI]);
      xrow[(size_t)t * DI] = y;
    }
  } else {
    for (int t = 0; t < TC; ++t) {
      const float* dr = &dsh[t * 48];
      float dtp = bd;
#pragma unroll
      for (int k = 0; k < 16; ++k) dtp = fmaf(dr[k], wdt[k], dtp);
      const float dtv = softplus_f(dtp);
      const float xsv = xrow[(size_t)t * DI];
      const float u = dtv * xsv;
      float y = 0.f;
#pragma unroll
      for (int s = 0; s < NSTATE; ++s) {
        const float a = __expf(dtv * Aa[s]);
        st[s] = fmaf(a, st[s], u * dr[16 + s]);
        y = fmaf(st[s], dr[32 + s], y);
      }
      y = fmaf(xsv, Dp, y);
      y *= silu_f(grow[(size_t)t * DI]);
      xrow[(size_t)t * DI] = y;
    }
  }
}

// ---------------------------------------------------------------------------
// Kernel 8 (fused combine + out-proj), v2: 32 t-rows x 128 c-cols per block.
// ---------------------------------------------------------------------------
__global__ __launch_bounds__(256, 2) void k_gemm_out(const float* __restrict__ y,
                                                     const float* __restrict__ Wout,
                                                     float* __restrict__ out) {
  __shared__ float Ash[64 * 33];
  __shared__ float Bsh[64 * 132];
  const int bx = blockIdx.x;                 // 0..255 : b*128 + tt
  const int b = bx >> 7, tt = bx & 127;
  const int t0 = tt << 5;                    // 32 rows
  const int c0 = blockIdx.y << 7;            // 128 cols
  const int tid = threadIdx.x;
  const int h = t0 >> 6, hf = 63 - h;        // constant per block
  const int w0 = t0 & 63;
  const int ar = tid >> 3, ak = tid & 7;
  const int w = w0 + ar, wf = 63 - w;
  const size_t row0 = ((size_t)(0 + b) * LSEQ + (h << 6) + w) * DI;
  const size_t row1 = ((size_t)(2 + b) * LSEQ + (h << 6) + wf) * DI;
  const size_t row2 = ((size_t)(4 + b) * LSEQ + (hf << 6) + w) * DI;
  const size_t row3 = ((size_t)(6 + b) * LSEQ + (hf << 6) + wf) * DI;
  const int bk = tid >> 3, bc = tid & 7;
  const int tx = tid & 31, cy = tid >> 5;    // 8 c-groups of 16 cols
  float acc[16];
#pragma unroll
  for (int j = 0; j < 16; ++j) acc[j] = 0.f;

  for (int kc = 0; kc < 512; kc += 64) {
#pragma unroll
    for (int f = 0; f < 2; ++f) {
      const int kl = (ak << 3) + (f << 2);
      const int k = kl + kc;
      const float4 v0 = *(const float4*)&y[row0 + k];
      const float4 v1 = *(const float4*)&y[row1 + k];
      const float4 v2 = *(const float4*)&y[row2 + k];
      const float4 v3 = *(const float4*)&y[row3 + k];
      Ash[(kl + 0) * 33 + ar] = 0.25f * (v0.x + v1.x + v2.x + v3.x);
      Ash[(kl + 1) * 33 + ar] = 0.25f * (v0.y + v1.y + v2.y + v3.y);
      Ash[(kl + 2) * 33 + ar] = 0.25f * (v0.z + v1.z + v2.z + v3.z);
      Ash[(kl + 3) * 33 + ar] = 0.25f * (v0.w + v1.w + v2.w + v3.w);
    }
#pragma unroll
    for (int rr = 0; rr < 2; ++rr) {
      const int kk = bk + (rr << 5);
#pragma unroll
      for (int i = 0; i < 4; ++i) {
        const int c = (bc << 2) + (i << 5);
        *(float4*)&Bsh[kk * 132 + c] =
            *(const float4*)&Wout[(size_t)(kc + kk) * 256 + c0 + c];
      }
    }
    __syncthreads();
#pragma unroll
    for (int kk = 0; kk < 64; ++kk) {
      const float a = Ash[kk * 33 + tx];
      const float* bp = &Bsh[kk * 132 + (cy << 4)];
      const float4 b0 = *(const float4*)&bp[0];
      const float4 b1 = *(const float4*)&bp[4];
      const float4 b2 = *(const float4*)&bp[8];
      const float4 b3 = *(const float4*)&bp[12];
      acc[0]  = fmaf(a, b0.x, acc[0]);   acc[1]  = fmaf(a, b0.y, acc[1]);
      acc[2]  = fmaf(a, b0.z, acc[2]);   acc[3]  = fmaf(a, b0.w, acc[3]);
      acc[4]  = fmaf(a, b1.x, acc[4]);   acc[5]  = fmaf(a, b1.y, acc[5]);
      acc[6]  = fmaf(a, b1.z, acc[6]);   acc[7]  = fmaf(a, b1.w, acc[7]);
      acc[8]  = fmaf(a, b2.x, acc[8]);   acc[9]  = fmaf(a, b2.y, acc[9]);
      acc[10] = fmaf(a, b2.z, acc[10]);  acc[11] = fmaf(a, b2.w, acc[11]);
      acc[12] = fmaf(a, b3.x, acc[12]);  acc[13] = fmaf(a, b3.y, acc[13]);
      acc[14] = fmaf(a, b3.z, acc[14]);  acc[15] = fmaf(a, b3.w, acc[15]);
    }
    __syncthreads();
  }
#pragma unroll
  for (int j = 0; j < 16; ++j) {
    const int c = c0 + (cy << 4) + j;
    out[((size_t)b * 256 + c) * LSEQ + t0 + tx] = acc[j];
  }
}

// ---------------------------------------------------------------------------
extern "C" void kernel_launch(void* const* d_in, const int* in_sizes, int n_in,
                              void* d_out, int out_size, void* d_ws, size_t ws_size,
                              hipStream_t stream) {
  const float* x     = (const float*)d_in[0];
  const float* W_in  = (const float*)d_in[1];
  const float* convw = (const float*)d_in[2];
  const float* convb = (const float*)d_in[3];
  const float* W_x   = (const float*)d_in[4];
  const float* W_dt  = (const float*)d_in[5];
  const float* b_dt  = (const float*)d_in[6];
  const float* A_log = (const float*)d_in[7];
  const float* Dvec  = (const float*)d_in[8];
  const float* W_out = (const float*)d_in[9];
  float* out = (float*)d_out;

  float* ws   = (float*)d_ws;
  float* xm   = ws + XM_OFF;
  float* gate = ws + GATE_OFF;
  float* xs   = ws + XS_OFF;
  float* dbl  = ws + DBL_OFF;
  float* wxT  = ws + WXT_OFF;
  float* ap   = ws + AP_OFF;   // aliases xm (dead after convx)
  float* ps   = ws + PS_OFF;   // aliases xm upper half

  // bf16-split buffers (dead after gemm_in)
  u16* xTh   = (u16*)(ws + SPLIT_OFF);   // [2][4096][256] bf16
  u16* xTl   = xTh + 2097152;
  u16* WinTh = xTl + 2097152;            // [1024][256] bf16
  u16* WinTl = WinTh + 262144;

  k_split<<<dim3(64, 4, 2), 256, 0, stream>>>(x, xTh, xTl, 256, 4096);
  k_split<<<dim3(16, 4, 1), 256, 0, stream>>>(W_in, WinTh, WinTl, 256, 1024);
  k_wxT<<<dim3(96), 256, 0, stream>>>(W_x, wxT);
  k_gemm_in_mfma<<<dim3(256, 8), 256, 0, stream>>>(xTh, xTl, WinTh, WinTl, xm, gate);
  k_convx<<<dim3(2048), 256, 0, stream>>>(xm, convw, convb, wxT, xs, dbl);
  k_scan1<<<dim3(NCH, 8, 2), 256, 0, stream>>>(xs, dbl, W_dt, b_dt, A_log, ap, ps);
  k_scan2<<<dim3(256), 256, 0, stream>>>(ap, ps);
  k_scan3<<<dim3(NCH, 8, 2), 256, 0, stream>>>(gate, xs, dbl, W_dt, b_dt, A_log, Dvec, ps);
  k_gemm_out<<<dim3(256, 2), 256, 0, stream>>>(xs, W_out, out);
}